// Round 1
// baseline (97.544 us; speedup 1.0000x reference)
//
#include <hip/hip_runtime.h>

// Problem constants (match reference)
#define BB 4096
#define DD 16
#define MM 4
#define RR 2048
#define CC 10
#define TB 4            // batch rows per block
#define RPT (RR / 256)  // rules per thread = 8

// ---------------- prep kernel: Wsum^T + packed rule codes ----------------
// WsumT[c][r] = sum_j consequents[r][j][c]   (transposed for coalesced reads)
// codes[r]    = 4 bytes, byte g = sum_k rules[r][4g+k] << (2k)
__global__ __launch_bounds__(256) void prep_kernel(
    const float* __restrict__ cons, const int* __restrict__ rules,
    float* __restrict__ wsumT, unsigned int* __restrict__ codes)
{
    int r = blockIdx.x * blockDim.x + threadIdx.x;
    if (r >= RR) return;
    const float* cr = cons + (size_t)r * (DD + 1) * CC;
    float s[CC];
#pragma unroll
    for (int c = 0; c < CC; ++c) s[c] = 0.0f;
#pragma unroll
    for (int j = 0; j < DD + 1; ++j) {
#pragma unroll
        for (int c = 0; c < CC; ++c) s[c] += cr[j * CC + c];
    }
#pragma unroll
    for (int c = 0; c < CC; ++c) wsumT[c * RR + r] = s[c];

    const int* rrp = rules + r * DD;
    unsigned int code = 0;
#pragma unroll
    for (int g = 0; g < 4; ++g) {
        unsigned int byte = 0;
#pragma unroll
        for (int k = 0; k < 4; ++k) byte |= (((unsigned int)rrp[g * 4 + k]) & 3u) << (2 * k);
        code |= byte << (8 * g);
    }
    codes[r] = code;
}

// ---------------- main kernel ----------------
// One block = 256 threads = 4 waves, owns TB=4 batch rows and ALL 2048 rules.
// LDS product tables: mf (64/row) -> pair (8x16/row) -> quad (4x256/row).
// fs[row][rule] = quad0[b0]*quad1[b1]*quad2[b2]*quad3[b3] via packed code.
__global__ __launch_bounds__(256) void anfis_main(
    const float* __restrict__ x, const float* __restrict__ centers,
    const float* __restrict__ widths, const float* __restrict__ wsumT,
    const unsigned int* __restrict__ codes,
    float* __restrict__ out, float* __restrict__ norm_fs, float* __restrict__ x_ext)
{
    // LDS: tables region (19456 B) aliased with reduction region (41120 B)
    __shared__ __align__(16) char smraw[40 * 257 * 4];
    float* sb = (float*)smraw;
#define MF(row, dm)     sb[(row) * 64 + (dm)]
#define PAIRT(row, p, e) sb[256 + (row) * 128 + (p) * 16 + (e)]
#define QUADT(row, g, e) sb[768 + (row) * 1024 + (g) * 256 + (e)]
#define RED(v, t)       sb[(v) * 257 + (t)]

    __shared__ float xs[TB][DD];
    __shared__ float sx[TB];
    __shared__ float wpart[4][TB];
    __shared__ float invl[TB];
    __shared__ float oscale[TB];
    __shared__ float part2[40][4];

    const int tid = threadIdx.x;
    const int b0 = blockIdx.x * TB;

    // ---- phase 1a: load x rows, emit x_ext ----
    if (tid < TB * DD) {
        int row = tid / DD, d = tid % DD;
        float v = x[(b0 + row) * DD + d];
        xs[row][d] = v;
        x_ext[(b0 + row) * (DD + 1) + d] = v;
    }
    if (tid < TB) x_ext[(b0 + tid) * (DD + 1) + DD] = 1.0f;
    __syncthreads();

    if (tid < TB) {
        float s = 1.0f;
#pragma unroll
        for (int d = 0; d < DD; ++d) s += xs[tid][d];
        sx[tid] = s;
    }

    // ---- phase 1b: membership values (one per thread: 4 rows x 64) ----
    {
        int row = tid >> 6, dm = tid & 63, d = dm >> 2, m = dm & 3;
        float c = centers[d * MM + m];
        float w = widths[d * MM + m];
        float z = xs[row][d] - c;
        MF(row, dm) = expf(-(z * z) / (2.0f * w * w));
    }
    __syncthreads();

    // ---- phase 1c: pair tables (512 entries) ----
#pragma unroll
    for (int i = tid; i < TB * 8 * 16; i += 256) {
        int row = i >> 7, rem = i & 127, p = rem >> 4, e = rem & 15;
        int i0 = e & 3, i1 = e >> 2;
        PAIRT(row, p, e) = MF(row, (2 * p) * 4 + i0) * MF(row, (2 * p + 1) * 4 + i1);
    }
    __syncthreads();

    // ---- phase 1d: quad tables (4096 entries) ----
#pragma unroll
    for (int i = tid; i < TB * 4 * 256; i += 256) {
        int row = i >> 10, rem = i & 1023, g = rem >> 8, e = rem & 255;
        int lo = e & 15, hi = e >> 4;
        QUADT(row, g, e) = PAIRT(row, 2 * g, lo) * PAIRT(row, 2 * g + 1, hi);
    }
    __syncthreads();

    // ---- phase 2: firing strengths + fused accumulation ----
    float fsreg[TB][RPT];
    float acc[TB][CC];
    float ssum[TB];
#pragma unroll
    for (int row = 0; row < TB; ++row) {
        ssum[row] = 0.0f;
#pragma unroll
        for (int c = 0; c < CC; ++c) acc[row][c] = 0.0f;
    }

#pragma unroll
    for (int j = 0; j < RPT; ++j) {
        int r = tid + 256 * j;
        unsigned int code = codes[r];
        float w[CC];
#pragma unroll
        for (int c = 0; c < CC; ++c) w[c] = wsumT[c * RR + r];
#pragma unroll
        for (int row = 0; row < TB; ++row) {
            float q0 = QUADT(row, 0, code & 255u);
            float q1 = QUADT(row, 1, (code >> 8) & 255u);
            float q2 = QUADT(row, 2, (code >> 16) & 255u);
            float q3 = QUADT(row, 3, code >> 24);
            float fs = (q0 * q1) * (q2 * q3);
            fsreg[row][j] = fs;
            ssum[row] += fs;
#pragma unroll
            for (int c = 0; c < CC; ++c) acc[row][c] = fmaf(fs, w[c], acc[row][c]);
        }
    }

    // ---- phase 3: per-row total across block ----
    const int lane = tid & 63;
    const int wv = tid >> 6;
#pragma unroll
    for (int row = 0; row < TB; ++row) {
        float s = ssum[row];
#pragma unroll
        for (int off = 32; off > 0; off >>= 1) s += __shfl_xor(s, off, 64);
        if (lane == 0) wpart[wv][row] = s;
    }
    __syncthreads();
    if (tid < TB) {
        float t = wpart[0][tid] + wpart[1][tid] + wpart[2][tid] + wpart[3][tid];
        float inv = 1.0f / (t + 1e-9f);
        invl[tid] = inv;
        oscale[tid] = sx[tid] * inv;
    }
    __syncthreads();

    // ---- phase 4: write norm_fs (coalesced) ----
#pragma unroll
    for (int row = 0; row < TB; ++row) {
        float inv = invl[row];
#pragma unroll
        for (int j = 0; j < RPT; ++j) {
            norm_fs[(size_t)(b0 + row) * RR + tid + 256 * j] = fsreg[row][j] * inv;
        }
    }

    // ---- phase 5: reduce acc[row][c] across 256 threads (LDS transpose-sum) ----
    // tables region no longer needed (all reads finished before phase-3 barrier)
#pragma unroll
    for (int row = 0; row < TB; ++row) {
#pragma unroll
        for (int c = 0; c < CC; ++c) {
            RED(row * CC + c, tid) = acc[row][c];
        }
    }
    __syncthreads();
    if (tid < 160) {
        int v = tid % 40, ch = tid / 40;  // 4 chunks of 64
        float s = 0.0f;
        int base = ch * 64;
        for (int i = 0; i < 64; ++i) s += RED(v, base + i);
        part2[v][ch] = s;
    }
    __syncthreads();
    if (tid < 40) {
        float val = part2[tid][0] + part2[tid][1] + part2[tid][2] + part2[tid][3];
        int row = tid / CC, c = tid % CC;
        out[(b0 + row) * CC + c] = oscale[row] * val;
    }
#undef MF
#undef PAIRT
#undef QUADT
#undef RED
}

// ---------------- launch ----------------
extern "C" void kernel_launch(void* const* d_in, const int* in_sizes, int n_in,
                              void* d_out, int out_size, void* d_ws, size_t ws_size,
                              hipStream_t stream) {
    const float* x       = (const float*)d_in[0];
    const float* centers = (const float*)d_in[1];
    const float* widths  = (const float*)d_in[2];
    const float* cons    = (const float*)d_in[3];
    const int*   rules   = (const int*)d_in[4];

    float* out_p     = (float*)d_out;                       // (B, C)
    float* norm_fs_p = out_p + (size_t)BB * CC;             // (B, R)
    float* x_ext_p   = norm_fs_p + (size_t)BB * RR;         // (B, D+1)

    float* wsumT = (float*)d_ws;                            // 10*2048 floats
    unsigned int* codes = (unsigned int*)((char*)d_ws + (size_t)CC * RR * sizeof(float));

    prep_kernel<<<(RR + 255) / 256, 256, 0, stream>>>(cons, rules, wsumT, codes);
    anfis_main<<<BB / TB, 256, 0, stream>>>(x, centers, widths, wsumT, codes,
                                            out_p, norm_fs_p, x_ext_p);
}

// Round 2
// 91.005 us; speedup vs baseline: 1.0719x; 1.0719x over previous
//
#include <hip/hip_runtime.h>

// Problem constants (match reference)
#define BB 4096
#define DD 16
#define MM 4
#define RR 2048
#define CC 10
#define TB 4            // batch rows per block
#define RPT (RR / 256)  // rules per thread = 8

typedef __attribute__((ext_vector_type(4))) float f32x4;

// ---------------- prep kernel ----------------
// wsumT[c][r] = sum_j cons[r][j][c]  (transposed for coalesced phase-2 reads)
// codes[r]   = packed 2-bit membership indices, byte g = dims 4g..4g+3
// Parallelism: one thread per (r,c) pair -> 20480 threads, 80 blocks.
__global__ __launch_bounds__(256) void prep_kernel(
    const float* __restrict__ cons, const int* __restrict__ rules,
    float* __restrict__ wsumT, unsigned int* __restrict__ codes)
{
    int gid = blockIdx.x * 256 + threadIdx.x;
    if (gid < RR * CC) {
        int r = gid / CC, c = gid - r * CC;   // c fastest -> lanes read ~40B runs
        const float* cr = cons + (size_t)r * (DD + 1) * CC + c;
        float s = 0.0f;
#pragma unroll
        for (int j = 0; j < DD + 1; ++j) s += cr[j * CC];
        wsumT[c * RR + r] = s;
    }
    if (gid < RR) {
        const int* rrp = rules + gid * DD;
        unsigned int code = 0;
#pragma unroll
        for (int g = 0; g < 4; ++g) {
            unsigned int byt = 0;
#pragma unroll
            for (int k = 0; k < 4; ++k)
                byt |= (((unsigned int)rrp[g * 4 + k]) & 3u) << (2 * k);
            code |= byt << (8 * g);
        }
        codes[gid] = code;
    }
}

// ---------------- main kernel ----------------
// One block = 256 threads = 4 waves, owns TB=4 batch rows and ALL 2048 rules.
// LDS product tables interleaved by ROW so one ds_read_b128 serves all 4 rows
// (rule code is row-independent): mf -> pair(f32x4) -> quad(f32x4).
__global__ __launch_bounds__(256) void anfis_main(
    const float* __restrict__ x, const float* __restrict__ centers,
    const float* __restrict__ widths, const float* __restrict__ wsumT,
    const unsigned int* __restrict__ codes,
    float* __restrict__ out, float* __restrict__ norm_fs, float* __restrict__ x_ext)
{
    __shared__ float MF[TB][64];        // 1 KB   [row][d*4+m]
    __shared__ f32x4 PAIR4[8][16];      // 2 KB   [p][i0+4*i1] -> rows
    __shared__ f32x4 QUAD4[4][256];     // 16 KB  [g][e] -> rows
    __shared__ float RED[TB * CC][68];  // 10.9 KB (40 x 64 cols, +4 pad)
    __shared__ float xs[TB][DD];
    __shared__ float sx[TB];
    __shared__ float wpart[4][TB];
    __shared__ float invl[TB];
    __shared__ float oscale[TB];
    __shared__ float part2[TB * CC][4];

    const int tid = threadIdx.x;
    const int b0 = blockIdx.x * TB;
    const int lane = tid & 63;
    const int wv = tid >> 6;

    // ---- phase 1a: load x rows, emit x_ext ----
    if (tid < TB * DD) {
        int row = tid / DD, d = tid % DD;
        float v = x[(b0 + row) * DD + d];
        xs[row][d] = v;
        x_ext[(b0 + row) * (DD + 1) + d] = v;
    }
    if (tid < TB) x_ext[(b0 + tid) * (DD + 1) + DD] = 1.0f;
    __syncthreads();

    if (tid < TB) {
        float s = 1.0f;
#pragma unroll
        for (int d = 0; d < DD; ++d) s += xs[tid][d];
        sx[tid] = s;
    }

    // ---- phase 1b: membership values (one per thread: 4 rows x 64) ----
    {
        int row = tid >> 6, dm = tid & 63, d = dm >> 2, m = dm & 3;
        float c = centers[d * MM + m];
        float w = widths[d * MM + m];
        float z = xs[row][d] - c;
        MF[row][dm] = expf(-(z * z) / (2.0f * w * w));
    }
    __syncthreads();

    // ---- phase 1c: pair tables, row-interleaved ----
    if (tid < 8 * 16) {
        int p = tid >> 4, e = tid & 15;
        int i0 = e & 3, i1 = e >> 2;
        f32x4 v;
#pragma unroll
        for (int row = 0; row < TB; ++row)
            v[row] = MF[row][(2 * p) * 4 + i0] * MF[row][(2 * p + 1) * 4 + i1];
        PAIR4[p][e] = v;
    }
    __syncthreads();

    // ---- phase 1d: quad tables, row-interleaved (vector mul) ----
#pragma unroll
    for (int i = tid; i < 4 * 256; i += 256) {
        int g = i >> 8, e = i & 255;
        QUAD4[g][e] = PAIR4[2 * g][e & 15] * PAIR4[2 * g + 1][e >> 4];
    }
    __syncthreads();

    // ---- phase 2: firing strengths + fused accumulation ----
    float fsreg[TB][RPT];
    float acc[TB][CC];
    float ssum[TB];
#pragma unroll
    for (int row = 0; row < TB; ++row) {
        ssum[row] = 0.0f;
#pragma unroll
        for (int c = 0; c < CC; ++c) acc[row][c] = 0.0f;
    }

#pragma unroll
    for (int j = 0; j < RPT; ++j) {
        int r = tid + 256 * j;
        unsigned int code = codes[r];
        float w[CC];
#pragma unroll
        for (int c = 0; c < CC; ++c) w[c] = wsumT[c * RR + r];
        f32x4 q0 = QUAD4[0][code & 255u];
        f32x4 q1 = QUAD4[1][(code >> 8) & 255u];
        f32x4 q2 = QUAD4[2][(code >> 16) & 255u];
        f32x4 q3 = QUAD4[3][code >> 24];
#pragma unroll
        for (int row = 0; row < TB; ++row) {
            float fs = (q0[row] * q1[row]) * (q2[row] * q3[row]);
            fsreg[row][j] = fs;
            ssum[row] += fs;
#pragma unroll
            for (int c = 0; c < CC; ++c) acc[row][c] = fmaf(fs, w[c], acc[row][c]);
        }
    }

    // ---- phase 3: per-row fs total across block ----
#pragma unroll
    for (int row = 0; row < TB; ++row) {
        float s = ssum[row];
#pragma unroll
        for (int off = 32; off > 0; off >>= 1) s += __shfl_xor(s, off, 64);
        if (lane == 0) wpart[wv][row] = s;
    }
    __syncthreads();
    if (tid < TB) {
        float t = wpart[0][tid] + wpart[1][tid] + wpart[2][tid] + wpart[3][tid];
        float inv = 1.0f / (t + 1e-9f);
        invl[tid] = inv;
        oscale[tid] = sx[tid] * inv;
    }
    __syncthreads();

    // ---- phase 4: write norm_fs (coalesced) ----
#pragma unroll
    for (int row = 0; row < TB; ++row) {
        float inv = invl[row];
#pragma unroll
        for (int j = 0; j < RPT; ++j) {
            norm_fs[(size_t)(b0 + row) * RR + tid + 256 * j] = fsreg[row][j] * inv;
        }
    }

    // ---- phase 5: reduce acc[row][c] across 256 threads ----
    // 2-step quad shuffle first (DPP-friendly), then LDS tree on 64 columns.
#pragma unroll
    for (int row = 0; row < TB; ++row) {
#pragma unroll
        for (int c = 0; c < CC; ++c) {
            float s = acc[row][c];
            s += __shfl_xor(s, 1, 64);
            s += __shfl_xor(s, 2, 64);
            if ((lane & 3) == 0) RED[row * CC + c][wv * 16 + (lane >> 2)] = s;
        }
    }
    __syncthreads();
    if (tid < 160) {
        int v = tid % 40, ch = tid / 40;  // 4 chunks of 16 columns
        float s = 0.0f;
        int base = ch * 16;
#pragma unroll
        for (int i = 0; i < 16; ++i) s += RED[v][base + i];
        part2[v][ch] = s;
    }
    __syncthreads();
    if (tid < TB * CC) {
        float val = part2[tid][0] + part2[tid][1] + part2[tid][2] + part2[tid][3];
        int row = tid / CC, c = tid % CC;
        out[(b0 + row) * CC + c] = oscale[row] * val;
    }
}

// ---------------- launch ----------------
extern "C" void kernel_launch(void* const* d_in, const int* in_sizes, int n_in,
                              void* d_out, int out_size, void* d_ws, size_t ws_size,
                              hipStream_t stream) {
    const float* x       = (const float*)d_in[0];
    const float* centers = (const float*)d_in[1];
    const float* widths  = (const float*)d_in[2];
    const float* cons    = (const float*)d_in[3];
    const int*   rules   = (const int*)d_in[4];

    float* out_p     = (float*)d_out;                       // (B, C)
    float* norm_fs_p = out_p + (size_t)BB * CC;             // (B, R)
    float* x_ext_p   = norm_fs_p + (size_t)BB * RR;         // (B, D+1)

    float* wsumT = (float*)d_ws;                            // 10*2048 floats
    unsigned int* codes = (unsigned int*)((char*)d_ws + (size_t)CC * RR * sizeof(float));

    prep_kernel<<<(RR * CC + 255) / 256, 256, 0, stream>>>(cons, rules, wsumT, codes);
    anfis_main<<<BB / TB, 256, 0, stream>>>(x, centers, widths, wsumT, codes,
                                            out_p, norm_fs_p, x_ext_p);
}